// Round 2
// baseline (64971.320 us; speedup 1.0000x reference)
//
#include <hip/hip_runtime.h>
#include <math.h>

#define BB 128
#define HH 1024
#define TT 128

__device__ __forceinline__ float sigf(float x) { return 1.0f / (1.0f + expf(-x)); }

// ---------------- transpose: dst[n][koff+k] = src[k][n] ----------------
__global__ __launch_bounds__(256) void k_transpose(
    const float* __restrict__ src, int K, int N,
    float* __restrict__ dst, int ldd, int koff)
{
    __shared__ float tile[32][33];
    int n0 = blockIdx.x * 32, k0 = blockIdx.y * 32;
    int tx = threadIdx.x & 31, ty = threadIdx.x >> 5;
#pragma unroll
    for (int i = 0; i < 32; i += 8) {
        int k = k0 + ty + i, n = n0 + tx;
        tile[ty + i][tx] = (k < K && n < N) ? src[(size_t)k * N + n] : 0.f;
    }
    __syncthreads();
#pragma unroll
    for (int i = 0; i < 32; i += 8) {
        int n = n0 + ty + i, k = k0 + tx;
        if (n < N && k < K) dst[(size_t)n * ldd + koff + k] = tile[tx][ty + i];
    }
}

// ---------------- GEMM tile: C[m0+0..63][n0+0..15] = A(128xK) @ WT^T ----------------
// A is split into nsec sections of K=1024 (row-major, stride 1024), optional per-row
// scale on sections 1,2 (scales are exactly 0/1 -> bit-exact vs reference).
// WT is (Ntot x nsec*1024) row-major, k-contiguous.
__device__ __forceinline__ void gemm_tile64(
    const float* __restrict__ A0, const float* __restrict__ A1, const float* __restrict__ A2,
    const float* __restrict__ s1, const float* __restrict__ s2,
    int nsec, const float* __restrict__ WT, int Ntot,
    int n0, int m0,
    const float* __restrict__ bias, float* __restrict__ C, int ldc)
{
    __shared__ float As[64][68];
    __shared__ float Bs[16][68];
    const int tid = threadIdx.x;
    const int c = tid & 15;          // column within tile
    const int g = tid >> 4;          // row group (4 rows each)
    const int lrow = tid >> 4;       // load row base
    const int lk4 = (tid & 15) << 2; // load k offset (float4)
    const int ldw = nsec << 10;

    float acc[4] = {0.f, 0.f, 0.f, 0.f};

    const int nchunks = nsec << 4;   // (nsec*1024)/64
    for (int ch = 0; ch < nchunks; ++ch) {
        const int sec = ch >> 4;
        const int lk0 = (ch & 15) << 6;
        const float* Ab = (sec == 0) ? A0 : ((sec == 1) ? A1 : A2);
        const float* sv = (sec == 0) ? (const float*)nullptr : ((sec == 1) ? s1 : s2);
        // stage A: 64 rows x 64 k
#pragma unroll
        for (int p = 0; p < 4; ++p) {
            int r = lrow + p * 16;
            float4 v = *reinterpret_cast<const float4*>(Ab + (size_t)(m0 + r) * 1024 + lk0 + lk4);
            if (sv) {
                float sc = sv[m0 + r];
                v.x *= sc; v.y *= sc; v.z *= sc; v.w *= sc;
            }
            *reinterpret_cast<float4*>(&As[r][lk4]) = v;
        }
        // stage B: 16 n-rows x 64 k
        {
            int n = n0 + lrow;
            n = (n < Ntot) ? n : (Ntot - 1);
            *reinterpret_cast<float4*>(&Bs[lrow][lk4]) =
                *reinterpret_cast<const float4*>(WT + (size_t)n * ldw + (ch << 6) + lk4);
        }
        __syncthreads();
#pragma unroll
        for (int k4 = 0; k4 < 64; k4 += 4) {
            const float4 b4 = *reinterpret_cast<const float4*>(&Bs[c][k4]);
#pragma unroll
            for (int j = 0; j < 4; ++j) {
                const float4 a4 = *reinterpret_cast<const float4*>(&As[(g << 2) + j][k4]);
                acc[j] = fmaf(a4.x, b4.x, acc[j]);
                acc[j] = fmaf(a4.y, b4.y, acc[j]);
                acc[j] = fmaf(a4.z, b4.z, acc[j]);
                acc[j] = fmaf(a4.w, b4.w, acc[j]);
            }
        }
        __syncthreads();
    }
    int n = n0 + c;
    if (n < Ntot) {
        float bv = bias ? bias[n] : 0.f;
#pragma unroll
        for (int j = 0; j < 4; ++j)
            C[(size_t)(m0 + (g << 2) + j) * ldc + n] = acc[j] + bv;
    }
}

__global__ __launch_bounds__(256) void k_gemm3(
    const float* __restrict__ A0, const float* __restrict__ A1, const float* __restrict__ A2,
    const float* __restrict__ s1, const float* __restrict__ s2,
    int nsec, const float* __restrict__ WT, int Ntot,
    const float* __restrict__ bias, float* __restrict__ C, int ldc)
{
    int tile = blockIdx.x >> 1, half = blockIdx.x & 1;
    gemm_tile64(A0, A1, A2, s1, s2, nsec, WT, Ntot, tile * 16, half * 64, bias, C, ldc);
}

// ---------------- step-3 combined: pre2 GEMM + Ht_hat GEMM + gate ----------------
__global__ __launch_bounds__(256) void k_step3(
    const float* __restrict__ h0, const float* __restrict__ h1, const float* __restrict__ h2,
    const float* __restrict__ W3T, const float* __restrict__ b2, float* __restrict__ pre2,
    const float* __restrict__ WoT, const float* __restrict__ bout, float* __restrict__ Hhat,
    const float* __restrict__ WgT, const float* __restrict__ bgate, float* __restrict__ gate)
{
    int bid = blockIdx.x;
    if (bid < 896) {
        const float *A0, *A1, *WT, *bias; float* C;
        int nsec, Ntot, n0, m0, ldc;
        if (bid < 512) {                      // pre2 = [h2 | h1] @ [Whh2; Wih2]^T + b2
            A0 = h2; A1 = h1; WT = W3T; bias = b2; C = pre2;
            nsec = 2; Ntot = 4096; ldc = 4096;
            n0 = (bid >> 1) * 16; m0 = (bid & 1) * 64;
        } else {                              // Ht_hat = [h0;h1;h2] @ Wout^T + bout
            int q = bid - 512;
            int layer = q >> 7, r = q & 127;
            A0 = (layer == 0) ? h0 : ((layer == 1) ? h1 : h2); A1 = nullptr;
            WT = WoT; bias = bout; C = Hhat + (size_t)layer * BB * HH;
            nsec = 1; Ntot = 1024; ldc = 1024;
            n0 = (r >> 1) * 16; m0 = (r & 1) * 64;
        }
        gemm_tile64(A0, A1, nullptr, nullptr, nullptr, nsec, WT, Ntot, n0, m0, bias, C, ldc);
    } else {
        // gate[i][j] = sigmoid( sum_m sum_h Htmix[3i+m][h] * Wgate[m*1024+h][j] + bgate[j] )
        int gid = bid - 896;                  // 0..31
        int w = threadIdx.x >> 6;             // wave 0..3 -> one batch row each
        int lane = threadIdx.x & 63;
        int i = gid * 4 + w;                  // 0..127
        float s0 = 0.f, s1 = 0.f, s2 = 0.f;
        for (int m = 0; m < 3; ++m) {
            int row = 3 * i + m;              // 0..383, row of the (384,1024) mix view
            const float* hb = (row < 128) ? h0 : ((row < 256) ? h1 : h2);
            const float* base = hb + (size_t)(row & 127) * HH;
#pragma unroll
            for (int it = 0; it < 16; ++it) {
                int kk = lane + (it << 6);
                float v = base[kk];
                int k = m * HH + kk;
                s0 = fmaf(v, WgT[k], s0);
                s1 = fmaf(v, WgT[3072 + k], s1);
                s2 = fmaf(v, WgT[2 * 3072 + k], s2);
            }
        }
#pragma unroll
        for (int off = 32; off > 0; off >>= 1) {
            s0 += __shfl_xor(s0, off);
            s1 += __shfl_xor(s1, off);
            s2 += __shfl_xor(s2, off);
        }
        if (lane == 0) {
            gate[i * 3 + 0] = sigf(s0 + bgate[0]);
            gate[i * 3 + 1] = sigf(s1 + bgate[1]);
            gate[i * 3 + 2] = sigf(s2 + bgate[2]);
        }
    }
}

// ---------------- cell pointwise (all 3 layers) + output combine ----------------
// zt (z_tm1, own layer): null -> 0 ; zl (z_lm1): null -> 1 ; znew: null -> skip.
__global__ __launch_bounds__(256) void k_cell_out(
    const float* __restrict__ pre, int ldpre,
    float* __restrict__ hbuf, float* __restrict__ cbuf,
    const float* __restrict__ ztv, const float* __restrict__ zlv,
    float* __restrict__ znew,
    const int* __restrict__ length, int t,
    const float* __restrict__ Hhat, const float* __restrict__ gate,
    float* __restrict__ outp)
{
    int bid = blockIdx.x, tid = threadIdx.x;
    if (bid < BB) {
        int b = bid;
        float tm = (t < length[b]) ? 1.f : 0.f;
        float zt = ztv ? ztv[b] : 0.f;
        float zl = zlv ? zlv[b] : 1.f;
        float keep = 1.f - zt;
        float cp = keep * (1.f - zl);
        const float* pr = pre + (size_t)b * ldpre;
        int h4 = tid << 2;
        float4 fv = *reinterpret_cast<const float4*>(pr + h4);
        float4 iv = *reinterpret_cast<const float4*>(pr + HH + h4);
        float4 ov = *reinterpret_cast<const float4*>(pr + 2 * HH + h4);
        float4 gv = *reinterpret_cast<const float4*>(pr + 3 * HH + h4);
        float* hp = hbuf + (size_t)b * HH + h4;
        float* cc = cbuf + (size_t)b * HH + h4;
        float4 hprev = *reinterpret_cast<const float4*>(hp);
        float4 cprev = *reinterpret_cast<const float4*>(cc);
        float f[4]  = {fv.x, fv.y, fv.z, fv.w};
        float ii[4] = {iv.x, iv.y, iv.z, iv.w};
        float oo[4] = {ov.x, ov.y, ov.z, ov.w};
        float gg[4] = {gv.x, gv.y, gv.z, gv.w};
        float hpv[4] = {hprev.x, hprev.y, hprev.z, hprev.w};
        float cpv[4] = {cprev.x, cprev.y, cprev.z, cprev.w};
        float ho[4], co[4];
#pragma unroll
        for (int j = 0; j < 4; ++j) {
            float cn = keep * sigf(f[j]) * cpv[j] + sigf(ii[j]) * tanhf(gg[j]);
            float hn = sigf(oo[j]) * tanhf(cn);
            float hh = cp * hpv[j] + (1.f - cp) * hn;
            float cv = cp * cpv[j] + (1.f - cp) * cn;
            ho[j] = tm * hh + (1.f - tm) * hpv[j];
            co[j] = tm * cv + (1.f - tm) * cpv[j];
        }
        float4 hw = {ho[0], ho[1], ho[2], ho[3]};
        float4 cw = {co[0], co[1], co[2], co[3]};
        *reinterpret_cast<float4*>(hp) = hw;
        *reinterpret_cast<float4*>(cc) = cw;
        if (znew && tid == 0) {
            float z = pr[4 * HH];
            float hs = fminf(fmaxf((z + 1.f) * 0.5f, 0.f), 1.f);
            znew[b] = rintf(hs);   // round-half-even, matches jnp.round; z unmasked by tm
        }
    } else {
        // out[b][h] = sum_l gate_lin[l*128+b] * Hhat[l*128+b][h]   (reference's quirky indexing)
        int b = bid - BB;
        int h4 = tid << 2;
        float a0 = 0.f, a1 = 0.f, a2 = 0.f, a3 = 0.f;
#pragma unroll
        for (int l = 0; l < 3; ++l) {
            float gl = gate[l * BB + b];
            const float4 v = *reinterpret_cast<const float4*>(Hhat + (size_t)(l * BB + b) * HH + h4);
            a0 = fmaf(gl, v.x, a0); a1 = fmaf(gl, v.y, a1);
            a2 = fmaf(gl, v.z, a2); a3 = fmaf(gl, v.w, a3);
        }
        float4 w = {a0, a1, a2, a3};
        *reinterpret_cast<float4*>(outp + (size_t)b * HH + h4) = w;
    }
}

extern "C" void kernel_launch(void* const* d_in, const int* in_sizes, int n_in,
                              void* d_out, int out_size, void* d_ws, size_t ws_size,
                              hipStream_t stream)
{
    (void)in_sizes; (void)n_in; (void)out_size;
    const float* input_ = (const float*)d_in[0];
    const int*   length = (const int*)d_in[1];
    const float* Wbh0 = (const float*)d_in[2];
    const float* Whh0 = (const float*)d_in[3];
    const float* Wth0 = (const float*)d_in[4];
    const float* b0   = (const float*)d_in[5];
    const float* Wbh1 = (const float*)d_in[6];
    const float* Whh1 = (const float*)d_in[7];
    const float* Wth1 = (const float*)d_in[8];
    const float* b1   = (const float*)d_in[9];
    const float* Wih2 = (const float*)d_in[10];
    const float* Whh2 = (const float*)d_in[11];
    const float* b2   = (const float*)d_in[12];
    const float* Wout = (const float*)d_in[13];
    const float* bout = (const float*)d_in[14];
    const float* Wgate= (const float*)d_in[15];
    const float* bgate= (const float*)d_in[16];
    float* out = (float*)d_out;

    // workspace budget guard: fail cleanly (no launches) rather than scribble OOB
    const size_t need_floats =
        (size_t)4097 * 3072 * 2 + (size_t)4096 * 2048 + (size_t)1024 * 1024 +
        (size_t)3 * 3072 + (size_t)BB * 4100 * 2 + (size_t)BB * 4096 +
        (size_t)384 * 1024 + 384 + (size_t)6 * BB * HH + 512;
    if (ws_size < need_floats * sizeof(float)) return;

    float* ws = (float*)d_ws;
    size_t off = 0;
    auto alloc = [&](size_t n) { float* p = ws + off; off += n; return p; };
    float* W1T  = alloc((size_t)4097 * 3072);   // [Wbh0; Whh0; Wth0]^T
    float* W2T  = alloc((size_t)4097 * 3072);   // [Whh1; Wbh1; Wth1]^T
    float* W3T  = alloc((size_t)4096 * 2048);   // [Whh2; Wih2]^T
    float* WoT  = alloc((size_t)1024 * 1024);   // Wout^T
    float* WgT  = alloc((size_t)3 * 3072);      // Wgate^T
    float* pre0 = alloc((size_t)BB * 4100);
    float* pre1 = alloc((size_t)BB * 4100);
    float* pre2 = alloc((size_t)BB * 4096);
    float* Hhat = alloc((size_t)384 * 1024);
    float* gate = alloc(384);
    float* h0 = alloc(BB * HH); float* c0 = alloc(BB * HH);
    float* h1 = alloc(BB * HH); float* c1 = alloc(BB * HH);
    float* h2 = alloc(BB * HH); float* c2 = alloc(BB * HH);
    float* z0 = alloc(256);                     // ping-pong [2][128]
    float* z1 = alloc(256);

    dim3 tb(256);
    auto T32 = [&](const float* src, int K, int N, float* dst, int ldd, int koff) {
        dim3 g((N + 31) / 32, K / 32);
        k_transpose<<<g, tb, 0, stream>>>(src, K, N, dst, ldd, koff);
    };
    T32(Wbh0, 1024, 4097, W1T, 3072, 0);
    T32(Whh0, 1024, 4097, W1T, 3072, 1024);
    T32(Wth0, 1024, 4097, W1T, 3072, 2048);
    T32(Whh1, 1024, 4097, W2T, 3072, 0);
    T32(Wbh1, 1024, 4097, W2T, 3072, 1024);
    T32(Wth1, 1024, 4097, W2T, 3072, 2048);
    T32(Whh2, 1024, 4096, W3T, 2048, 0);
    T32(Wih2, 1024, 4096, W3T, 2048, 1024);
    T32(Wout, 1024, 1024, WoT, 1024, 0);
    T32(Wgate, 3072, 3, WgT, 3072, 0);

    // zero initial state (h0..z1 are contiguous)
    hipMemsetAsync(h0, 0, (size_t)(6 * BB * HH + 512) * sizeof(float), stream);

    for (int t = 0; t < TT; ++t) {
        int p = t & 1, q = p ^ 1;
        const float* xt = input_ + (size_t)t * BB * 1024;
        // layer 0: pre0 = [xt | h0 | z0_old*h1] @ [Wbh0;Whh0;Wth0]^T + b0
        k_gemm3<<<dim3(514), tb, 0, stream>>>(
            xt, h0, h1, (const float*)nullptr, z0 + p * BB,
            3, W1T, 4097, b0, pre0, 4100);
        k_cell_out<<<dim3(128), tb, 0, stream>>>(
            pre0, 4100, h0, c0, z0 + p * BB, (const float*)nullptr, z0 + q * BB,
            length, t, (const float*)nullptr, (const float*)nullptr, (float*)nullptr);
        // layer 1: pre1 = [h1 | z0_new*h0 | z1_old*h2] @ [Whh1;Wbh1;Wth1]^T + b1
        k_gemm3<<<dim3(514), tb, 0, stream>>>(
            h1, h0, h2, z0 + q * BB, z1 + p * BB,
            3, W2T, 4097, b1, pre1, 4100);
        k_cell_out<<<dim3(128), tb, 0, stream>>>(
            pre1, 4100, h1, c1, z1 + p * BB, z0 + q * BB, z1 + q * BB,
            length, t, (const float*)nullptr, (const float*)nullptr, (float*)nullptr);
        // layer 2 pre + Ht_hat + gate (h2 still old here)
        k_step3<<<dim3(928), tb, 0, stream>>>(
            h0, h1, h2, W3T, b2, pre2, WoT, bout, Hhat, WgT, bgate, gate);
        // layer 2 cell (cp = 1 - z0_new) + output combine
        k_cell_out<<<dim3(256), tb, 0, stream>>>(
            pre2, 4096, h2, c2, (const float*)nullptr, z0 + q * BB, (float*)nullptr,
            length, t, Hhat, gate, out + (size_t)t * BB * HH);
    }
}